// Round 21
// baseline (209.213 us; speedup 1.0000x reference)
//
#include <hip/hip_runtime.h>
#include <hip/hip_bf16.h>
#include <stdint.h>
#include <string.h>

#define EMBED 1024
#define HEADS 16
#define HD    64
#define SEQ   2048
#define NB    4
#define ROWS  (SEQ * NB)   // 8192
#define NH    (NB * HEADS) // 64

typedef __attribute__((ext_vector_type(8)))  short short8;   // 8 x bf16
typedef __attribute__((ext_vector_type(4)))  float f32x4;
typedef __attribute__((ext_vector_type(16))) float f32x16;
typedef __attribute__((ext_vector_type(4)))  unsigned short u16x4;

#define MFMA16(a, b, c) __builtin_amdgcn_mfma_f32_16x16x32_bf16((a), (b), (c), 0, 0, 0)
#define MFMA32(a, b, c) __builtin_amdgcn_mfma_f32_32x32x16_bf16((a), (b), (c), 0, 0, 0)

// fp32 -> bf16 bits, round-to-nearest-even
__device__ inline unsigned short f2b(float f) {
    unsigned u = __builtin_bit_cast(unsigned, f);
    u += 0x7fffu + ((u >> 16) & 1u);
    return (unsigned short)(u >> 16);
}

// packed pair fp32 -> bf16x2 via the COMPILER's conversion (RNE, lo = a).
__device__ inline unsigned pk2(float a, float b) {
    __hip_bfloat162 h = __float22bfloat162_rn(make_float2(a, b));
    unsigned r;
    __builtin_memcpy(&r, &h, 4);
    return r;
}

// raw v_exp_f32: D = 2^S0 (large-negative -> 0)
#define EXP2(x) __builtin_amdgcn_exp2f(x)

__device__ inline short8 ld8(const unsigned short* p) {
    return *reinterpret_cast<const short8*>(p);
}

// ---------------------------------------------------------------------------
// Kernel 0: fp32 -> bf16 cast (for Wo)
// ---------------------------------------------------------------------------
__global__ __launch_bounds__(256) void cvt_bf16_kernel(const float* __restrict__ in,
                                                       unsigned short* __restrict__ out,
                                                       int nelem) {
    int i = (blockIdx.x * 256 + threadIdx.x) * 4;
    if (i + 3 < nelem) {
        float4 v = *reinterpret_cast<const float4*>(in + i);
        u16x4 o;
        o[0] = f2b(v.x); o[1] = f2b(v.y); o[2] = f2b(v.z); o[3] = f2b(v.w);
        *reinterpret_cast<u16x4*>(out + i) = o;
    }
}

// ---------------------------------------------------------------------------
// Kernel 0b: pack mask (N,SEQ) int -> bit words, word w covers k = w*32..+31
// ---------------------------------------------------------------------------
__global__ __launch_bounds__(64) void maskbits_kernel(const int* __restrict__ mask,
                                                      unsigned* __restrict__ mb) {
    int w = blockIdx.x * 64 + threadIdx.x;   // 256 words total
    unsigned v = 0;
#pragma unroll
    for (int j = 0; j < 32; ++j)
        v |= (mask[w * 32 + j] != 0 ? 1u : 0u) << j;
    mb[w] = v;
}

// ---------------------------------------------------------------------------
// Kernel 1: per-head projection  out = X_head @ W.T  via MFMA 16x16x32
// 64 rows per block (4 x 16-row sub-tiles; W loaded/converted ONCE).
// out layout [n*16+h][l][d]  (Q, K).  grid (ROWS/64, HEADS), block 64.
// ---------------------------------------------------------------------------
__global__ __launch_bounds__(64) void proj_kernel(const float* __restrict__ X,
                                                  const float* __restrict__ W,
                                                  unsigned short* __restrict__ out) {
    const int lane = threadIdx.x;
    const int lo = lane & 15, hi = lane >> 4;
    const int rb0 = blockIdx.x * 64;
    const int h   = blockIdx.y;

    // B fragments: W converted once per block
    short8 b[4][2];
#pragma unroll
    for (int u = 0; u < 4; ++u)
#pragma unroll
        for (int s = 0; s < 2; ++s) {
            const float4* src = reinterpret_cast<const float4*>(
                W + (size_t)(16 * u + lo) * HD + s * 32 + hi * 8);
            float4 v0 = src[0], v1 = src[1];
            short8 t;
            t[0] = (short)f2b(v0.x); t[1] = (short)f2b(v0.y);
            t[2] = (short)f2b(v0.z); t[3] = (short)f2b(v0.w);
            t[4] = (short)f2b(v1.x); t[5] = (short)f2b(v1.y);
            t[6] = (short)f2b(v1.z); t[7] = (short)f2b(v1.w);
            b[u][s] = t;
        }

    const int n  = rb0 >> 11;
    const int l0 = rb0 & (SEQ - 1);
    const size_t nh = (size_t)(n * HEADS + h);
    unsigned short* ob = out + nh * (SEQ * HD);

#pragma unroll
    for (int rt = 0; rt < 4; ++rt) {
        const int r0 = rb0 + rt * 16;
        short8 a[2];
#pragma unroll
        for (int s = 0; s < 2; ++s) {
            const float4* src = reinterpret_cast<const float4*>(
                X + (size_t)(r0 + lo) * EMBED + h * HD + s * 32 + hi * 8);
            float4 v0 = src[0], v1 = src[1];
            short8 t;
            t[0] = (short)f2b(v0.x); t[1] = (short)f2b(v0.y);
            t[2] = (short)f2b(v0.z); t[3] = (short)f2b(v0.w);
            t[4] = (short)f2b(v1.x); t[5] = (short)f2b(v1.y);
            t[6] = (short)f2b(v1.z); t[7] = (short)f2b(v1.w);
            a[s] = t;
        }

        f32x4 acc[4] = {};
#pragma unroll
        for (int u = 0; u < 4; ++u)
#pragma unroll
            for (int s = 0; s < 2; ++s)
                acc[u] = MFMA16(a[s], b[u][s], acc[u]);

#pragma unroll
        for (int u = 0; u < 4; ++u)
#pragma unroll
            for (int r = 0; r < 4; ++r)
                ob[(size_t)(l0 + rt * 16 + hi * 4 + r) * HD + 16 * u + lo] =
                    f2b(acc[u][r]);
    }
}

// ---------------------------------------------------------------------------
// Kernel 1b: V projection with transposed output [n*16+h][d][l].
// ---------------------------------------------------------------------------
__global__ __launch_bounds__(256) void projv_kernel(const float* __restrict__ X,
                                                    const float* __restrict__ W,
                                                    unsigned short* __restrict__ out) {
    const int tid = threadIdx.x;
    const int w = tid >> 6, lane = tid & 63;
    const int lo = lane & 15, hi = lane >> 4;
    const int r0 = blockIdx.x * 64;
    const int rw = r0 + w * 16;
    const int h  = blockIdx.y;

    __shared__ unsigned short T[64 * 73];

    short8 a[2];
#pragma unroll
    for (int s = 0; s < 2; ++s) {
        const float4* src = reinterpret_cast<const float4*>(
            X + (size_t)(rw + lo) * EMBED + h * HD + s * 32 + hi * 8);
        float4 v0 = src[0], v1 = src[1];
        short8 t;
        t[0] = (short)f2b(v0.x); t[1] = (short)f2b(v0.y);
        t[2] = (short)f2b(v0.z); t[3] = (short)f2b(v0.w);
        t[4] = (short)f2b(v1.x); t[5] = (short)f2b(v1.y);
        t[6] = (short)f2b(v1.z); t[7] = (short)f2b(v1.w);
        a[s] = t;
    }
    short8 b[4][2];
#pragma unroll
    for (int u = 0; u < 4; ++u)
#pragma unroll
        for (int s = 0; s < 2; ++s) {
            const float4* src = reinterpret_cast<const float4*>(
                W + (size_t)(16 * u + lo) * HD + s * 32 + hi * 8);
            float4 v0 = src[0], v1 = src[1];
            short8 t;
            t[0] = (short)f2b(v0.x); t[1] = (short)f2b(v0.y);
            t[2] = (short)f2b(v0.z); t[3] = (short)f2b(v0.w);
            t[4] = (short)f2b(v1.x); t[5] = (short)f2b(v1.y);
            t[6] = (short)f2b(v1.z); t[7] = (short)f2b(v1.w);
            b[u][s] = t;
        }

    f32x4 acc[4] = {};
#pragma unroll
    for (int u = 0; u < 4; ++u)
#pragma unroll
        for (int s = 0; s < 2; ++s)
            acc[u] = MFMA16(a[s], b[u][s], acc[u]);

#pragma unroll
    for (int u = 0; u < 4; ++u)
#pragma unroll
        for (int r = 0; r < 4; ++r)
            T[(w * 16 + hi * 4 + r) * 73 + 16 * u + lo] = f2b(acc[u][r]);
    __syncthreads();

    const int d = tid >> 2, lc = (tid & 3) * 16;
    const int n = r0 >> 11, l0 = r0 & (SEQ - 1);
    union { unsigned short s[16]; uint4 v[2]; } pk;
#pragma unroll
    for (int j = 0; j < 16; ++j) pk.s[j] = T[(lc + j) * 73 + d];
    unsigned short* dst = out + (size_t)(n * HEADS + h) * (HD * SEQ)
                              + (size_t)d * SEQ + l0 + lc;
    *reinterpret_cast<uint4*>(dst)     = pk.v[0];
    *reinterpret_cast<uint4*>(dst + 8) = pk.v[1];
}

// ---------------------------------------------------------------------------
// Kernel 2: flash attention — R20 math; ONLY delta: quad-buffered k-tile
// PAIRING. Pair p uses buffer set p&1 (bufs {2s, 2s+1}); writes of pair p+1
// go to the other set -> single barrier per pair is race-free (drift <= 1).
// Barriers halve (32 total) and each compute phase holds 2 independent tiles.
// ---------------------------------------------------------------------------
#define KST 72   // K LDS row stride (elems)
#define VST 40   // V LDS row stride (elems)

__global__ __launch_bounds__(128) void attn_kernel(const unsigned short* __restrict__ Qb,
                                                   const unsigned short* __restrict__ Kb,
                                                   const unsigned short* __restrict__ Vt,
                                                   const unsigned* __restrict__ mbits,
                                                   unsigned short* __restrict__ Aout) {
    const int tid  = threadIdx.x;
    const int w    = tid >> 6;           // 0..1
    const int lane = tid & 63;
    const int lo = lane & 31, hi = lane >> 5;
    const int nhidx = blockIdx.y;
    const int n = nhidx >> 4, h = nhidx & 15;
    const int q0 = blockIdx.x * 128 + w * 64;

    const unsigned short* Qp = Qb + (size_t)nhidx * SEQ * HD;
    const unsigned short* Kp = Kb + (size_t)nhidx * SEQ * HD;
    const unsigned short* Vp = Vt + (size_t)nhidx * HD * SEQ;
    const unsigned* mb = mbits + n * (SEQ / 32);

    __shared__ __align__(16) unsigned short Klds[4][32 * KST];
    __shared__ __align__(16) unsigned short Vlds[4][64 * VST];

    // staging chunks: thread t owns chunks 2t, 2t+1 (same row, adjacent 16B)
    const int kr = (tid * 2) >> 3, kb0 = ((tid * 2) & 7) * 8;
    const int vr = (tid * 2) >> 2, vb0 = ((tid * 2) & 3) * 8;  // vb0 in {0,16}

    uint4 sK0a, sK0b, sV0a, sV0b;   // staging set 0 (even tile of pair)
    uint4 sK1a, sK1b, sV1a, sV1b;   // staging set 1 (odd tile of pair)
#define LOADSTAGE(KB_, KA, KBv, VA, VB)                                       \
    {                                                                         \
        const unsigned short* kp_ = Kp + (size_t)((KB_) + kr) * HD + kb0;     \
        const unsigned short* vp_ = Vp + (size_t)vr * SEQ + (KB_) + vb0;      \
        KA  = *reinterpret_cast<const uint4*>(kp_);                           \
        KBv = *reinterpret_cast<const uint4*>(kp_ + 8);                       \
        VA  = *reinterpret_cast<const uint4*>(vp_);                           \
        VB  = *reinterpret_cast<const uint4*>(vp_ + 8);                       \
    }
    // V written pre-permuted within its 16-col group:
    //   lo-half = {V0.x,V0.y,V1.z,V1.w} ; hi-half = {V0.z,V0.w,V1.x,V1.y}
#define WRITESTAGE(BUF, KA, KBv, VA, VB)                                      \
    {                                                                         \
        *reinterpret_cast<uint4*>(&Klds[BUF][kr * KST + kb0])     = KA;       \
        *reinterpret_cast<uint4*>(&Klds[BUF][kr * KST + kb0 + 8]) = KBv;      \
        uint4 pv0, pv1;                                                       \
        pv0.x = VA.x; pv0.y = VA.y; pv0.z = VB.z; pv0.w = VB.w;               \
        pv1.x = VA.z; pv1.y = VA.w; pv1.z = VB.x; pv1.w = VB.y;               \
        *reinterpret_cast<uint4*>(&Vlds[BUF][vr * VST + vb0])     = pv0;      \
        *reinterpret_cast<uint4*>(&Vlds[BUF][vr * VST + vb0 + 8]) = pv1;      \
    }

    // Q fragments (B-operand of swapped QK^T), two q-groups:
    //   A: col = q0+lo, B: col = q0+32+lo ; k=d = s*16 + hi*8 + j
    short8 qfA[4], qfB[4];
#pragma unroll
    for (int s = 0; s < 4; ++s) {
        qfA[s] = ld8(Qp + (size_t)(q0 + lo) * HD + s * 16 + hi * 8);
        qfB[s] = ld8(Qp + (size_t)(q0 + 32 + lo) * HD + s * 16 + hi * 8);
    }

    f32x16 o0A = {}, o1A = {}, o0B = {}, o1B = {};
    float lsumA = 0.0f, lsumB = 0.0f;

    const float KS    = 0.045084220027780106f;  // log2(e)/32
    const float M0    = 8.0f;                   // static softmax shift (exact)
    const float TMASK = -4.5e18f;               // exp2 -> 0

    // one 32-k tile: QK^T, softmax, pack, PV
#define COMPUTE_TILE(KL, VL, MWORD)                                           \
    {                                                                         \
        const unsigned short* Kl = (KL);                                      \
        const unsigned short* Vl = (VL);                                      \
        f32x16 saA = {}, saB = {};                                            \
        _Pragma("unroll") for (int s = 0; s < 4; ++s) {                       \
            short8 kf = *reinterpret_cast<const short8*>(                     \
                Kl + lo * KST + s * 16 + hi * 8);                             \
            saA = MFMA32(kf, qfA[s], saA);                                    \
            saB = MFMA32(kf, qfB[s], saB);                                    \
        }                                                                     \
        short8 vf[2][2];                                                      \
        _Pragma("unroll") for (int dt = 0; dt < 2; ++dt)                      \
            _Pragma("unroll") for (int s = 0; s < 2; ++s)                     \
                vf[dt][s] = *reinterpret_cast<const short8*>(                 \
                    Vl + (32 * dt + lo) * VST + s * 16 + hi * 8);             \
        unsigned mw = (MWORD) >> (4 * hi);                                    \
        float pA[16], pB[16];                                                 \
        _Pragma("unroll") for (int r = 0; r < 16; ++r) {                      \
            const int bp = (r & 3) + 8 * (r >> 2);                            \
            const bool keep = (mw >> bp) & 1u;                                \
            float ta = fmaf(saA[r], KS, -M0);                                 \
            float tb = fmaf(saB[r], KS, -M0);                                 \
            float ea = EXP2(keep ? ta : TMASK);                               \
            float eb = EXP2(keep ? tb : TMASK);                               \
            pA[r] = ea; lsumA += ea;                                          \
            pB[r] = eb; lsumB += eb;                                          \
        }                                                                     \
        short8 pbA[2], pbB[2];                                                \
        {                                                                     \
            unsigned W0[4], W1[4];                                            \
            _Pragma("unroll") for (int g = 0; g < 4; ++g) {                   \
                W0[g] = pk2(pA[4 * g],     pA[4 * g + 1]);                    \
                W1[g] = pk2(pA[4 * g + 2], pA[4 * g + 3]);                    \
            }                                                                 \
            _Pragma("unroll") for (int s2 = 0; s2 < 2; ++s2) {                \
                unsigned sw0 = (unsigned)__shfl_xor((int)W0[2 * s2 + 1], 32); \
                unsigned sw1 = (unsigned)__shfl_xor((int)W1[2 * s2 + 1], 32); \
                union { short8 s8; unsigned u[4]; } uu;                       \
                uu.u[0] = W0[2 * s2]; uu.u[1] = W1[2 * s2];                   \
                uu.u[2] = sw0;        uu.u[3] = sw1;                          \
                pbA[s2] = uu.s8;                                              \
            }                                                                 \
        }                                                                     \
        {                                                                     \
            unsigned W0[4], W1[4];                                            \
            _Pragma("unroll") for (int g = 0; g < 4; ++g) {                   \
                W0[g] = pk2(pB[4 * g],     pB[4 * g + 1]);                    \
                W1[g] = pk2(pB[4 * g + 2], pB[4 * g + 3]);                    \
            }                                                                 \
            _Pragma("unroll") for (int s2 = 0; s2 < 2; ++s2) {                \
                unsigned sw0 = (unsigned)__shfl_xor((int)W0[2 * s2 + 1], 32); \
                unsigned sw1 = (unsigned)__shfl_xor((int)W1[2 * s2 + 1], 32); \
                union { short8 s8; unsigned u[4]; } uu;                       \
                uu.u[0] = W0[2 * s2]; uu.u[1] = W1[2 * s2];                   \
                uu.u[2] = sw0;        uu.u[3] = sw1;                          \
                pbB[s2] = uu.s8;                                              \
            }                                                                 \
        }                                                                     \
        _Pragma("unroll") for (int s = 0; s < 2; ++s) {                       \
            o0A = MFMA32(vf[0][s], pbA[s], o0A);                              \
            o1A = MFMA32(vf[1][s], pbA[s], o1A);                              \
            o0B = MFMA32(vf[0][s], pbB[s], o0B);                              \
            o1B = MFMA32(vf[1][s], pbB[s], o1B);                              \
        }                                                                     \
    }

    LOADSTAGE(0,  sK0a, sK0b, sV0a, sV0b)
    LOADSTAGE(32, sK1a, sK1b, sV1a, sV1b)

    int base = 0;   // buffer set base: 0 or 2
    for (int p = 0; p < 32; ++p) {
        WRITESTAGE(base,     sK0a, sK0b, sV0a, sV0b)
        WRITESTAGE(base + 1, sK1a, sK1b, sV1a, sV1b)
        if (p + 1 < 32) {
            LOADSTAGE(p * 64 + 64, sK0a, sK0b, sV0a, sV0b)
            LOADSTAGE(p * 64 + 96, sK1a, sK1b, sV1a, sV1b)
        }
        __syncthreads();   // single barrier per pair (quad-buffer safe)

        COMPUTE_TILE(Klds[base],     Vlds[base],     mb[2 * p])
        COMPUTE_TILE(Klds[base + 1], Vlds[base + 1], mb[2 * p + 1])

        base ^= 2;
    }
#undef COMPUTE_TILE

    // final cross-half reduce of the denominators
    float lA = lsumA + __shfl_xor(lsumA, 32);
    float lB = lsumB + __shfl_xor(lsumB, 32);

    // epilogue: group A owns q = q0+lo, group B owns q = q0+32+lo
    float invA = 1.0f / lA;
    float invB = 1.0f / lB;
    const size_t rbA = (size_t)(n * SEQ + q0 + lo) * EMBED + h * HD;
    const size_t rbB = (size_t)(n * SEQ + q0 + 32 + lo) * EMBED + h * HD;
#pragma unroll
    for (int r = 0; r < 16; ++r) {
        int dl = (r & 3) + 8 * (r >> 2) + 4 * hi;
        Aout[rbA + dl]      = f2b(o0A[r] * invA);
        Aout[rbA + 32 + dl] = f2b(o1A[r] * invA);
        Aout[rbB + dl]      = f2b(o0B[r] * invB);
        Aout[rbB + 32 + dl] = f2b(o1B[r] * invB);
    }
#undef LOADSTAGE
#undef WRITESTAGE
}

// ---------------------------------------------------------------------------
// Kernel 3: Y = A(8192x1024) @ Wo.T + bo  (fp32 out), LDS-staged GEMM.
// R19 version (flat grid + XCD swizzle).
// ---------------------------------------------------------------------------
#define OST 40
__global__ __launch_bounds__(256, 2) void outproj_kernel(const unsigned short* __restrict__ A,
                                                         const unsigned short* __restrict__ Wob,
                                                         const float* __restrict__ bo,
                                                         float* __restrict__ Y) {
    const int tid  = threadIdx.x;
    const int w    = tid >> 6;
    const int lane = tid & 63;
    const int lo = lane & 15, hi = lane >> 4;

    const int bid = blockIdx.x;                    // 0..511
    const int swz = (bid & 7) * 64 + (bid >> 3);   // bijective bit-rotation
    const int r0 = (swz >> 3) * 128;
    const int c0 = (swz & 7) * 128;

    __shared__ __align__(16) unsigned short Al[128 * OST];
    __shared__ __align__(16) unsigned short Bl[128 * OST];

    const int srow = tid >> 2, scb = (tid & 3) * 8;
    uint4 sA0, sA1, sB0, sB1;
#define OLOAD(K_)                                                             \
    {                                                                         \
        sA0 = *reinterpret_cast<const uint4*>(A + (size_t)(r0 + srow) * EMBED + (K_) + scb);        \
        sA1 = *reinterpret_cast<const uint4*>(A + (size_t)(r0 + 64 + srow) * EMBED + (K_) + scb);   \
        sB0 = *reinterpret_cast<const uint4*>(Wob + (size_t)(c0 + srow) * EMBED + (K_) + scb);      \
        sB1 = *reinterpret_cast<const uint4*>(Wob + (size_t)(c0 + 64 + srow) * EMBED + (K_) + scb); \
    }
#define OWRITE()                                                              \
    {                                                                         \
        *reinterpret_cast<uint4*>(&Al[srow * OST + scb])        = sA0;        \
        *reinterpret_cast<uint4*>(&Al[(64 + srow) * OST + scb]) = sA1;        \
        *reinterpret_cast<uint4*>(&Bl[srow * OST + scb])        = sB0;        \
        *reinterpret_cast<uint4*>(&Bl[(64 + srow) * OST + scb]) = sB1;        \
    }

    f32x4 acc[2][8] = {};
    OLOAD(0)
    for (int kt = 0; kt < EMBED / 32; ++kt) {
        OWRITE()
        if (kt + 1 < EMBED / 32) OLOAD((kt + 1) * 32)
        __syncthreads();

        short8 a0 = ld8(&Al[(w * 32 + lo) * OST + hi * 8]);
        short8 a1 = ld8(&Al[(w * 32 + 16 + lo) * OST + hi * 8]);
#pragma unroll
        for (int u = 0; u < 8; ++u) {
            short8 b = ld8(&Bl[(u * 16 + lo) * OST + hi * 8]);
            acc[0][u] = MFMA16(a0, b, acc[0][u]);
            acc[1][u] = MFMA16(a1, b, acc[1][u]);
        }
        __syncthreads();
    }

#pragma unroll
    for (int mi = 0; mi < 2; ++mi)
#pragma unroll
        for (int u = 0; u < 8; ++u) {
            int e = c0 + u * 16 + lo;
            float bv = bo[e];
#pragma unroll
            for (int r = 0; r < 4; ++r)
                Y[(size_t)(r0 + w * 32 + mi * 16 + hi * 4 + r) * EMBED + e] =
                    acc[mi][u][r] + bv;
        }
#undef OLOAD
#undef OWRITE
}

// ---------------------------------------------------------------------------
extern "C" void kernel_launch(void* const* d_in, const int* in_sizes, int n_in,
                              void* d_out, int out_size, void* d_ws, size_t ws_size,
                              hipStream_t stream) {
    const float* values  = (const float*)d_in[0];
    const float* keys    = (const float*)d_in[1];
    const float* queries = (const float*)d_in[2];
    const int*   mask    = (const int*)d_in[3];
    const float* Wv = (const float*)d_in[4];
    const float* Wk = (const float*)d_in[5];
    const float* Wq = (const float*)d_in[6];
    const float* Wo = (const float*)d_in[7];
    const float* bo = (const float*)d_in[8];
    float* Y = (float*)d_out;

    const size_t QKV     = (size_t)NH * SEQ * HD * sizeof(unsigned short); // 16 MiB
    const size_t ABYTES  = (size_t)ROWS * EMBED * sizeof(unsigned short);  // 16 MiB
    const size_t WOBYTES = (size_t)EMBED * EMBED * sizeof(unsigned short); //  2 MiB
    const size_t MBYTES  = (size_t)NB * (SEQ / 32) * sizeof(unsigned);
    if (ws_size < 3 * QKV + ABYTES + WOBYTES + MBYTES) return;

    char* ws = (char*)d_ws;
    unsigned short* Qb  = (unsigned short*)(ws);
    unsigned short* Kb  = (unsigned short*)(ws + QKV);
    unsigned short* Vt  = (unsigned short*)(ws + 2 * QKV);
    unsigned short* Ab  = (unsigned short*)(ws + 3 * QKV);
    unsigned short* Wob = (unsigned short*)(ws + 3 * QKV + ABYTES);
    unsigned*       Mb  = (unsigned*)(ws + 3 * QKV + ABYTES + WOBYTES);

    cvt_bf16_kernel<<<dim3(EMBED * EMBED / (256 * 4)), 256, 0, stream>>>(Wo, Wob, EMBED * EMBED);
    maskbits_kernel<<<dim3(4), 64, 0, stream>>>(mask, Mb);
    proj_kernel<<<dim3(ROWS / 64, HEADS), 64, 0, stream>>>(queries, Wq, Qb);
    proj_kernel<<<dim3(ROWS / 64, HEADS), 64, 0, stream>>>(keys,    Wk, Kb);
    projv_kernel<<<dim3(ROWS / 64, HEADS), 256, 0, stream>>>(values, Wv, Vt);
    attn_kernel<<<dim3(SEQ / 128, NH), 128, 0, stream>>>(Qb, Kb, Vt, Mb, Ab);
    outproj_kernel<<<dim3(512), 256, 0, stream>>>(Ab, Wob, bo, Y);
}

// Round 22
// 185.281 us; speedup vs baseline: 1.1292x; 1.1292x over previous
//
#include <hip/hip_runtime.h>
#include <hip/hip_bf16.h>
#include <stdint.h>
#include <string.h>

#define EMBED 1024
#define HEADS 16
#define HD    64
#define SEQ   2048
#define NB    4
#define ROWS  (SEQ * NB)   // 8192
#define NH    (NB * HEADS) // 64

typedef __attribute__((ext_vector_type(8)))  short short8;   // 8 x bf16
typedef __attribute__((ext_vector_type(4)))  float f32x4;
typedef __attribute__((ext_vector_type(16))) float f32x16;
typedef __attribute__((ext_vector_type(4)))  unsigned short u16x4;

#define MFMA16(a, b, c) __builtin_amdgcn_mfma_f32_16x16x32_bf16((a), (b), (c), 0, 0, 0)
#define MFMA32(a, b, c) __builtin_amdgcn_mfma_f32_32x32x16_bf16((a), (b), (c), 0, 0, 0)

// fp32 -> bf16 bits, round-to-nearest-even
__device__ inline unsigned short f2b(float f) {
    unsigned u = __builtin_bit_cast(unsigned, f);
    u += 0x7fffu + ((u >> 16) & 1u);
    return (unsigned short)(u >> 16);
}

// packed pair fp32 -> bf16x2 via the COMPILER's conversion (RNE, lo = a).
__device__ inline unsigned pk2(float a, float b) {
    __hip_bfloat162 h = __float22bfloat162_rn(make_float2(a, b));
    unsigned r;
    __builtin_memcpy(&r, &h, 4);
    return r;
}

// raw v_exp_f32: D = 2^S0 (large-negative -> 0)
#define EXP2(x) __builtin_amdgcn_exp2f(x)

__device__ inline short8 ld8(const unsigned short* p) {
    return *reinterpret_cast<const short8*>(p);
}

// ---------------------------------------------------------------------------
// Kernel 0: fp32 -> bf16 cast (for Wo)
// ---------------------------------------------------------------------------
__global__ __launch_bounds__(256) void cvt_bf16_kernel(const float* __restrict__ in,
                                                       unsigned short* __restrict__ out,
                                                       int nelem) {
    int i = (blockIdx.x * 256 + threadIdx.x) * 4;
    if (i + 3 < nelem) {
        float4 v = *reinterpret_cast<const float4*>(in + i);
        u16x4 o;
        o[0] = f2b(v.x); o[1] = f2b(v.y); o[2] = f2b(v.z); o[3] = f2b(v.w);
        *reinterpret_cast<u16x4*>(out + i) = o;
    }
}

// ---------------------------------------------------------------------------
// Kernel 0b: pack mask (N,SEQ) int -> bit words, word w covers k = w*32..+31
// ---------------------------------------------------------------------------
__global__ __launch_bounds__(64) void maskbits_kernel(const int* __restrict__ mask,
                                                      unsigned* __restrict__ mb) {
    int w = blockIdx.x * 64 + threadIdx.x;   // 256 words total
    unsigned v = 0;
#pragma unroll
    for (int j = 0; j < 32; ++j)
        v |= (mask[w * 32 + j] != 0 ? 1u : 0u) << j;
    mb[w] = v;
}

// ---------------------------------------------------------------------------
// Kernel 1: per-head projection  out = X_head @ W.T  via MFMA 16x16x32
// 64 rows per block (4 x 16-row sub-tiles; W loaded/converted ONCE).
// out layout [n*16+h][l][d]  (Q, K).  grid (ROWS/64, HEADS), block 64.
// ---------------------------------------------------------------------------
__global__ __launch_bounds__(64) void proj_kernel(const float* __restrict__ X,
                                                  const float* __restrict__ W,
                                                  unsigned short* __restrict__ out) {
    const int lane = threadIdx.x;
    const int lo = lane & 15, hi = lane >> 4;
    const int rb0 = blockIdx.x * 64;
    const int h   = blockIdx.y;

    // B fragments: W converted once per block
    short8 b[4][2];
#pragma unroll
    for (int u = 0; u < 4; ++u)
#pragma unroll
        for (int s = 0; s < 2; ++s) {
            const float4* src = reinterpret_cast<const float4*>(
                W + (size_t)(16 * u + lo) * HD + s * 32 + hi * 8);
            float4 v0 = src[0], v1 = src[1];
            short8 t;
            t[0] = (short)f2b(v0.x); t[1] = (short)f2b(v0.y);
            t[2] = (short)f2b(v0.z); t[3] = (short)f2b(v0.w);
            t[4] = (short)f2b(v1.x); t[5] = (short)f2b(v1.y);
            t[6] = (short)f2b(v1.z); t[7] = (short)f2b(v1.w);
            b[u][s] = t;
        }

    const int n  = rb0 >> 11;
    const int l0 = rb0 & (SEQ - 1);
    const size_t nh = (size_t)(n * HEADS + h);
    unsigned short* ob = out + nh * (SEQ * HD);

#pragma unroll
    for (int rt = 0; rt < 4; ++rt) {
        const int r0 = rb0 + rt * 16;
        short8 a[2];
#pragma unroll
        for (int s = 0; s < 2; ++s) {
            const float4* src = reinterpret_cast<const float4*>(
                X + (size_t)(r0 + lo) * EMBED + h * HD + s * 32 + hi * 8);
            float4 v0 = src[0], v1 = src[1];
            short8 t;
            t[0] = (short)f2b(v0.x); t[1] = (short)f2b(v0.y);
            t[2] = (short)f2b(v0.z); t[3] = (short)f2b(v0.w);
            t[4] = (short)f2b(v1.x); t[5] = (short)f2b(v1.y);
            t[6] = (short)f2b(v1.z); t[7] = (short)f2b(v1.w);
            a[s] = t;
        }

        f32x4 acc[4] = {};
#pragma unroll
        for (int u = 0; u < 4; ++u)
#pragma unroll
            for (int s = 0; s < 2; ++s)
                acc[u] = MFMA16(a[s], b[u][s], acc[u]);

#pragma unroll
        for (int u = 0; u < 4; ++u)
#pragma unroll
            for (int r = 0; r < 4; ++r)
                ob[(size_t)(l0 + rt * 16 + hi * 4 + r) * HD + 16 * u + lo] =
                    f2b(acc[u][r]);
    }
}

// ---------------------------------------------------------------------------
// Kernel 1b: V projection with transposed output [n*16+h][d][l].
// ---------------------------------------------------------------------------
__global__ __launch_bounds__(256) void projv_kernel(const float* __restrict__ X,
                                                    const float* __restrict__ W,
                                                    unsigned short* __restrict__ out) {
    const int tid = threadIdx.x;
    const int w = tid >> 6, lane = tid & 63;
    const int lo = lane & 15, hi = lane >> 4;
    const int r0 = blockIdx.x * 64;
    const int rw = r0 + w * 16;
    const int h  = blockIdx.y;

    __shared__ unsigned short T[64 * 73];

    short8 a[2];
#pragma unroll
    for (int s = 0; s < 2; ++s) {
        const float4* src = reinterpret_cast<const float4*>(
            X + (size_t)(rw + lo) * EMBED + h * HD + s * 32 + hi * 8);
        float4 v0 = src[0], v1 = src[1];
        short8 t;
        t[0] = (short)f2b(v0.x); t[1] = (short)f2b(v0.y);
        t[2] = (short)f2b(v0.z); t[3] = (short)f2b(v0.w);
        t[4] = (short)f2b(v1.x); t[5] = (short)f2b(v1.y);
        t[6] = (short)f2b(v1.z); t[7] = (short)f2b(v1.w);
        a[s] = t;
    }
    short8 b[4][2];
#pragma unroll
    for (int u = 0; u < 4; ++u)
#pragma unroll
        for (int s = 0; s < 2; ++s) {
            const float4* src = reinterpret_cast<const float4*>(
                W + (size_t)(16 * u + lo) * HD + s * 32 + hi * 8);
            float4 v0 = src[0], v1 = src[1];
            short8 t;
            t[0] = (short)f2b(v0.x); t[1] = (short)f2b(v0.y);
            t[2] = (short)f2b(v0.z); t[3] = (short)f2b(v0.w);
            t[4] = (short)f2b(v1.x); t[5] = (short)f2b(v1.y);
            t[6] = (short)f2b(v1.z); t[7] = (short)f2b(v1.w);
            b[u][s] = t;
        }

    f32x4 acc[4] = {};
#pragma unroll
    for (int u = 0; u < 4; ++u)
#pragma unroll
        for (int s = 0; s < 2; ++s)
            acc[u] = MFMA16(a[s], b[u][s], acc[u]);

#pragma unroll
    for (int u = 0; u < 4; ++u)
#pragma unroll
        for (int r = 0; r < 4; ++r)
            T[(w * 16 + hi * 4 + r) * 73 + 16 * u + lo] = f2b(acc[u][r]);
    __syncthreads();

    const int d = tid >> 2, lc = (tid & 3) * 16;
    const int n = r0 >> 11, l0 = r0 & (SEQ - 1);
    union { unsigned short s[16]; uint4 v[2]; } pk;
#pragma unroll
    for (int j = 0; j < 16; ++j) pk.s[j] = T[(lc + j) * 73 + d];
    unsigned short* dst = out + (size_t)(n * HEADS + h) * (HD * SEQ)
                              + (size_t)d * SEQ + l0 + lc;
    *reinterpret_cast<uint4*>(dst)     = pk.v[0];
    *reinterpret_cast<uint4*>(dst + 8) = pk.v[1];
}

// ---------------------------------------------------------------------------
// Kernel 2: flash attention — R20/best version: padded linear LDS, KVB=32,
// dual-buffered with a SINGLE barrier per tile, pre-permuted V staging,
// static softmax shift, pk2 pack, QBLK=64 x 2 waves, grid (16, NH).
// ---------------------------------------------------------------------------
#define KST 72   // K LDS row stride (elems)
#define VST 40   // V LDS row stride (elems)

__global__ __launch_bounds__(128, 2) void attn_kernel(const unsigned short* __restrict__ Qb,
                                                      const unsigned short* __restrict__ Kb,
                                                      const unsigned short* __restrict__ Vt,
                                                      const unsigned* __restrict__ mbits,
                                                      unsigned short* __restrict__ Aout) {
    const int tid  = threadIdx.x;
    const int w    = tid >> 6;           // 0..1
    const int lane = tid & 63;
    const int lo = lane & 31, hi = lane >> 5;
    const int nhidx = blockIdx.y;
    const int n = nhidx >> 4, h = nhidx & 15;
    const int q0 = blockIdx.x * 128 + w * 64;

    const unsigned short* Qp = Qb + (size_t)nhidx * SEQ * HD;
    const unsigned short* Kp = Kb + (size_t)nhidx * SEQ * HD;
    const unsigned short* Vp = Vt + (size_t)nhidx * HD * SEQ;
    const unsigned* mb = mbits + n * (SEQ / 32);

    __shared__ __align__(16) unsigned short Klds[2][32 * KST];
    __shared__ __align__(16) unsigned short Vlds[2][64 * VST];

    // staging chunks: thread t owns chunks 2t, 2t+1 (same row, adjacent 16B)
    const int kr = (tid * 2) >> 3, kb0 = ((tid * 2) & 7) * 8;
    const int vr = (tid * 2) >> 2, vb0 = ((tid * 2) & 3) * 8;  // vb0 in {0,16}

    uint4 stK0, stK1, stV0, stV1;
#define LOADSTAGE(KB_)                                                        \
    {                                                                         \
        const unsigned short* kp_ = Kp + (size_t)((KB_) + kr) * HD + kb0;     \
        const unsigned short* vp_ = Vp + (size_t)vr * SEQ + (KB_) + vb0;      \
        stK0 = *reinterpret_cast<const uint4*>(kp_);                          \
        stK1 = *reinterpret_cast<const uint4*>(kp_ + 8);                      \
        stV0 = *reinterpret_cast<const uint4*>(vp_);                          \
        stV1 = *reinterpret_cast<const uint4*>(vp_ + 8);                      \
    }
    // V written pre-permuted within its 16-col group:
    //   lo-half = {V0.x,V0.y,V1.z,V1.w} ; hi-half = {V0.z,V0.w,V1.x,V1.y}
#define WRITESTAGE(BUF)                                                       \
    {                                                                         \
        *reinterpret_cast<uint4*>(&Klds[BUF][kr * KST + kb0])     = stK0;     \
        *reinterpret_cast<uint4*>(&Klds[BUF][kr * KST + kb0 + 8]) = stK1;     \
        uint4 pv0, pv1;                                                       \
        pv0.x = stV0.x; pv0.y = stV0.y; pv0.z = stV1.z; pv0.w = stV1.w;       \
        pv1.x = stV0.z; pv1.y = stV0.w; pv1.z = stV1.x; pv1.w = stV1.y;       \
        *reinterpret_cast<uint4*>(&Vlds[BUF][vr * VST + vb0])     = pv0;      \
        *reinterpret_cast<uint4*>(&Vlds[BUF][vr * VST + vb0 + 8]) = pv1;      \
    }

    // Q fragments (B-operand of swapped QK^T), two q-groups:
    //   A: col = q0+lo, B: col = q0+32+lo ; k=d = s*16 + hi*8 + j
    short8 qfA[4], qfB[4];
#pragma unroll
    for (int s = 0; s < 4; ++s) {
        qfA[s] = ld8(Qp + (size_t)(q0 + lo) * HD + s * 16 + hi * 8);
        qfB[s] = ld8(Qp + (size_t)(q0 + 32 + lo) * HD + s * 16 + hi * 8);
    }

    f32x16 o0A = {}, o1A = {}, o0B = {}, o1B = {};
    float lsumA = 0.0f, lsumB = 0.0f;

    const float KS    = 0.045084220027780106f;  // log2(e)/32
    const float M0    = 8.0f;                   // static softmax shift (exact)
    const float TMASK = -4.5e18f;               // exp2 -> 0

    LOADSTAGE(0)

    int cur = 0;
    for (int kt = 0; kt < SEQ / 32; ++kt) {
        WRITESTAGE(cur)
        if (kt + 1 < SEQ / 32) LOADSTAGE((kt + 1) * 32)
        __syncthreads();   // the ONLY barrier per tile

        const unsigned short* Kl = Klds[cur];
        const unsigned short* Vl = Vlds[cur];

        // S^T = K . Q^T : A-operand = K rows (row = k_local = lo), shared
        f32x16 saA = {}, saB = {};
#pragma unroll
        for (int s = 0; s < 4; ++s) {
            short8 kf = *reinterpret_cast<const short8*>(Kl + lo * KST + s * 16 + hi * 8);
            saA = MFMA32(kf, qfA[s], saA);
            saB = MFMA32(kf, qfB[s], saB);
        }

        // V^T fragments: ONE b128 each from the pre-permuted LDS layout
        short8 vf[2][2];
#pragma unroll
        for (int dt = 0; dt < 2; ++dt)
#pragma unroll
            for (int s = 0; s < 2; ++s)
                vf[dt][s] = *reinterpret_cast<const short8*>(
                    Vl + (32 * dt + lo) * VST + s * 16 + hi * 8);

        // masked, scaled, statically-shifted logits -> exp2 (both q-groups)
        unsigned mw = mb[kt] >> (4 * hi);
        float pA[16], pB[16];
#pragma unroll
        for (int r = 0; r < 16; ++r) {
            const int bp = (r & 3) + 8 * (r >> 2);
            const bool keep = (mw >> bp) & 1u;
            float ta = fmaf(saA[r], KS, -M0);
            float tb = fmaf(saB[r], KS, -M0);
            float ea = EXP2(keep ? ta : TMASK);
            float eb = EXP2(keep ? tb : TMASK);
            pA[r] = ea; lsumA += ea;
            pB[r] = eb; lsumB += eb;
        }

        // pack P and build P^T B-fragments (same pi permutation), per group
#define PACK_PB(P, PB_)                                                       \
        {                                                                     \
            unsigned W0[4], W1[4];                                            \
            _Pragma("unroll") for (int g = 0; g < 4; ++g) {                   \
                W0[g] = pk2(P[4 * g],     P[4 * g + 1]);                      \
                W1[g] = pk2(P[4 * g + 2], P[4 * g + 3]);                      \
            }                                                                 \
            _Pragma("unroll") for (int s2 = 0; s2 < 2; ++s2) {                \
                unsigned sw0 = (unsigned)__shfl_xor((int)W0[2 * s2 + 1], 32); \
                unsigned sw1 = (unsigned)__shfl_xor((int)W1[2 * s2 + 1], 32); \
                union { short8 s8; unsigned u[4]; } uu;                       \
                uu.u[0] = W0[2 * s2]; uu.u[1] = W1[2 * s2];                   \
                uu.u[2] = sw0;        uu.u[3] = sw1;                          \
                (PB_)[s2] = uu.s8;                                            \
            }                                                                 \
        }
        short8 pbA[2], pbB[2];
        PACK_PB(pA, pbA)
        PACK_PB(pB, pbB)
#undef PACK_PB

        // O^T += V^T . P^T  (V fragments shared across q-groups)
#pragma unroll
        for (int s = 0; s < 2; ++s) {
            o0A = MFMA32(vf[0][s], pbA[s], o0A);
            o1A = MFMA32(vf[1][s], pbA[s], o1A);
            o0B = MFMA32(vf[0][s], pbB[s], o0B);
            o1B = MFMA32(vf[1][s], pbB[s], o1B);
        }

        cur ^= 1;   // no end-of-loop barrier needed (disjoint buffers)
    }

    // final cross-half reduce of the denominators
    float lA = lsumA + __shfl_xor(lsumA, 32);
    float lB = lsumB + __shfl_xor(lsumB, 32);

    // epilogue: group A owns q = q0+lo, group B owns q = q0+32+lo
    float invA = 1.0f / lA;
    float invB = 1.0f / lB;
    const size_t rbA = (size_t)(n * SEQ + q0 + lo) * EMBED + h * HD;
    const size_t rbB = (size_t)(n * SEQ + q0 + 32 + lo) * EMBED + h * HD;
#pragma unroll
    for (int r = 0; r < 16; ++r) {
        int dl = (r & 3) + 8 * (r >> 2) + 4 * hi;
        Aout[rbA + dl]      = f2b(o0A[r] * invA);
        Aout[rbA + 32 + dl] = f2b(o1A[r] * invA);
        Aout[rbB + dl]      = f2b(o0B[r] * invB);
        Aout[rbB + 32 + dl] = f2b(o1B[r] * invB);
    }
#undef LOADSTAGE
#undef WRITESTAGE
}

// ---------------------------------------------------------------------------
// Kernel 3: Y = A(8192x1024) @ Wo.T + bo  (fp32 out), LDS-staged GEMM.
// Flat grid + XCD swizzle (neutral but harmless), tile 128x128, BK=32.
// ---------------------------------------------------------------------------
#define OST 40
__global__ __launch_bounds__(256, 2) void outproj_kernel(const unsigned short* __restrict__ A,
                                                         const unsigned short* __restrict__ Wob,
                                                         const float* __restrict__ bo,
                                                         float* __restrict__ Y) {
    const int tid  = threadIdx.x;
    const int w    = tid >> 6;
    const int lane = tid & 63;
    const int lo = lane & 15, hi = lane >> 4;

    const int bid = blockIdx.x;                    // 0..511
    const int swz = (bid & 7) * 64 + (bid >> 3);   // bijective bit-rotation
    const int r0 = (swz >> 3) * 128;
    const int c0 = (swz & 7) * 128;

    __shared__ __align__(16) unsigned short Al[128 * OST];
    __shared__ __align__(16) unsigned short Bl[128 * OST];

    const int srow = tid >> 2, scb = (tid & 3) * 8;
    uint4 sA0, sA1, sB0, sB1;
#define OLOAD(K_)                                                             \
    {                                                                         \
        sA0 = *reinterpret_cast<const uint4*>(A + (size_t)(r0 + srow) * EMBED + (K_) + scb);        \
        sA1 = *reinterpret_cast<const uint4*>(A + (size_t)(r0 + 64 + srow) * EMBED + (K_) + scb);   \
        sB0 = *reinterpret_cast<const uint4*>(Wob + (size_t)(c0 + srow) * EMBED + (K_) + scb);      \
        sB1 = *reinterpret_cast<const uint4*>(Wob + (size_t)(c0 + 64 + srow) * EMBED + (K_) + scb); \
    }
#define OWRITE()                                                              \
    {                                                                         \
        *reinterpret_cast<uint4*>(&Al[srow * OST + scb])        = sA0;        \
        *reinterpret_cast<uint4*>(&Al[(64 + srow) * OST + scb]) = sA1;        \
        *reinterpret_cast<uint4*>(&Bl[srow * OST + scb])        = sB0;        \
        *reinterpret_cast<uint4*>(&Bl[(64 + srow) * OST + scb]) = sB1;        \
    }

    f32x4 acc[2][8] = {};
    OLOAD(0)
    for (int kt = 0; kt < EMBED / 32; ++kt) {
        OWRITE()
        if (kt + 1 < EMBED / 32) OLOAD((kt + 1) * 32)
        __syncthreads();

        short8 a0 = ld8(&Al[(w * 32 + lo) * OST + hi * 8]);
        short8 a1 = ld8(&Al[(w * 32 + 16 + lo) * OST + hi * 8]);
#pragma unroll
        for (int u = 0; u < 8; ++u) {
            short8 b = ld8(&Bl[(u * 16 + lo) * OST + hi * 8]);
            acc[0][u] = MFMA16(a0, b, acc[0][u]);
            acc[1][u] = MFMA16(a1, b, acc[1][u]);
        }
        __syncthreads();
    }

#pragma unroll
    for (int mi = 0; mi < 2; ++mi)
#pragma unroll
        for (int u = 0; u < 8; ++u) {
            int e = c0 + u * 16 + lo;
            float bv = bo[e];
#pragma unroll
            for (int r = 0; r < 4; ++r)
                Y[(size_t)(r0 + w * 32 + mi * 16 + hi * 4 + r) * EMBED + e] =
                    acc[mi][u][r] + bv;
        }
#undef OLOAD
#undef OWRITE
}

// ---------------------------------------------------------------------------
extern "C" void kernel_launch(void* const* d_in, const int* in_sizes, int n_in,
                              void* d_out, int out_size, void* d_ws, size_t ws_size,
                              hipStream_t stream) {
    const float* values  = (const float*)d_in[0];
    const float* keys    = (const float*)d_in[1];
    const float* queries = (const float*)d_in[2];
    const int*   mask    = (const int*)d_in[3];
    const float* Wv = (const float*)d_in[4];
    const float* Wk = (const float*)d_in[5];
    const float* Wq = (const float*)d_in[6];
    const float* Wo = (const float*)d_in[7];
    const float* bo = (const float*)d_in[8];
    float* Y = (float*)d_out;

    const size_t QKV     = (size_t)NH * SEQ * HD * sizeof(unsigned short); // 16 MiB
    const size_t ABYTES  = (size_t)ROWS * EMBED * sizeof(unsigned short);  // 16 MiB
    const size_t WOBYTES = (size_t)EMBED * EMBED * sizeof(unsigned short); //  2 MiB
    const size_t MBYTES  = (size_t)NB * (SEQ / 32) * sizeof(unsigned);
    if (ws_size < 3 * QKV + ABYTES + WOBYTES + MBYTES) return;

    char* ws = (char*)d_ws;
    unsigned short* Qb  = (unsigned short*)(ws);
    unsigned short* Kb  = (unsigned short*)(ws + QKV);
    unsigned short* Vt  = (unsigned short*)(ws + 2 * QKV);
    unsigned short* Ab  = (unsigned short*)(ws + 3 * QKV);
    unsigned short* Wob = (unsigned short*)(ws + 3 * QKV + ABYTES);
    unsigned*       Mb  = (unsigned*)(ws + 3 * QKV + ABYTES + WOBYTES);

    cvt_bf16_kernel<<<dim3(EMBED * EMBED / (256 * 4)), 256, 0, stream>>>(Wo, Wob, EMBED * EMBED);
    maskbits_kernel<<<dim3(4), 64, 0, stream>>>(mask, Mb);
    proj_kernel<<<dim3(ROWS / 64, HEADS), 64, 0, stream>>>(queries, Wq, Qb);
    proj_kernel<<<dim3(ROWS / 64, HEADS), 64, 0, stream>>>(keys,    Wk, Kb);
    projv_kernel<<<dim3(ROWS / 64, HEADS), 256, 0, stream>>>(values, Wv, Vt);
    attn_kernel<<<dim3(SEQ / 128, NH), 128, 0, stream>>>(Qb, Kb, Vt, Mb, Ab);
    outproj_kernel<<<dim3(512), 256, 0, stream>>>(Ab, Wob, bo, Y);
}

// Round 23
// 180.263 us; speedup vs baseline: 1.1606x; 1.0278x over previous
//
#include <hip/hip_runtime.h>
#include <hip/hip_bf16.h>
#include <stdint.h>
#include <string.h>

#define EMBED 1024
#define HEADS 16
#define HD    64
#define SEQ   2048
#define NB    4
#define ROWS  (SEQ * NB)   // 8192
#define NH    (NB * HEADS) // 64

typedef __attribute__((ext_vector_type(8)))  short short8;   // 8 x bf16
typedef __attribute__((ext_vector_type(4)))  float f32x4;
typedef __attribute__((ext_vector_type(16))) float f32x16;
typedef __attribute__((ext_vector_type(4)))  unsigned short u16x4;

#define MFMA16(a, b, c) __builtin_amdgcn_mfma_f32_16x16x32_bf16((a), (b), (c), 0, 0, 0)
#define MFMA32(a, b, c) __builtin_amdgcn_mfma_f32_32x32x16_bf16((a), (b), (c), 0, 0, 0)

// fp32 -> bf16 bits, round-to-nearest-even
__device__ inline unsigned short f2b(float f) {
    unsigned u = __builtin_bit_cast(unsigned, f);
    u += 0x7fffu + ((u >> 16) & 1u);
    return (unsigned short)(u >> 16);
}

// packed pair fp32 -> bf16x2 via the COMPILER's conversion (RNE, lo = a).
__device__ inline unsigned pk2(float a, float b) {
    __hip_bfloat162 h = __float22bfloat162_rn(make_float2(a, b));
    unsigned r;
    __builtin_memcpy(&r, &h, 4);
    return r;
}

// raw v_exp_f32: D = 2^S0 (large-negative -> 0)
#define EXP2(x) __builtin_amdgcn_exp2f(x)

__device__ inline short8 ld8(const unsigned short* p) {
    return *reinterpret_cast<const short8*>(p);
}

// ---------------------------------------------------------------------------
// Kernel 0: merged fp32->bf16 cast (Wo, blocks 0..1023) + mask bit-pack
// (block 1024: 256 threads, one 32-k mask word each).
// ---------------------------------------------------------------------------
__global__ __launch_bounds__(256) void cvtmask_kernel(const float* __restrict__ in,
                                                      unsigned short* __restrict__ out,
                                                      const int* __restrict__ mask,
                                                      unsigned* __restrict__ mb) {
    const int bid = blockIdx.x;
    if (bid < 1024) {
        int i = (bid * 256 + threadIdx.x) * 4;
        float4 v = *reinterpret_cast<const float4*>(in + i);
        u16x4 o;
        o[0] = f2b(v.x); o[1] = f2b(v.y); o[2] = f2b(v.z); o[3] = f2b(v.w);
        *reinterpret_cast<u16x4*>(out + i) = o;
    } else {
        int w = threadIdx.x;   // 256 words total
        unsigned v = 0;
#pragma unroll
        for (int j = 0; j < 32; ++j)
            v |= (mask[w * 32 + j] != 0 ? 1u : 0u) << j;
        mb[w] = v;
    }
}

// ---------------------------------------------------------------------------
// Kernel 1: merged Q/K per-head projection  out = X_head @ W.T (MFMA 16x16x32)
// blockIdx.z selects (X, W, out). 64 rows per block (4 x 16-row sub-tiles;
// W converted ONCE). out layout [n*16+h][l][d]. grid (ROWS/64, HEADS, 2).
// ---------------------------------------------------------------------------
__global__ __launch_bounds__(64) void projqk_kernel(const float* __restrict__ Xq,
                                                    const float* __restrict__ Wq,
                                                    unsigned short* __restrict__ outq,
                                                    const float* __restrict__ Xk,
                                                    const float* __restrict__ Wk,
                                                    unsigned short* __restrict__ outk) {
    const float* X = blockIdx.z ? Xk : Xq;
    const float* W = blockIdx.z ? Wk : Wq;
    unsigned short* out = blockIdx.z ? outk : outq;

    const int lane = threadIdx.x;
    const int lo = lane & 15, hi = lane >> 4;
    const int rb0 = blockIdx.x * 64;
    const int h   = blockIdx.y;

    // B fragments: W converted once per block
    short8 b[4][2];
#pragma unroll
    for (int u = 0; u < 4; ++u)
#pragma unroll
        for (int s = 0; s < 2; ++s) {
            const float4* src = reinterpret_cast<const float4*>(
                W + (size_t)(16 * u + lo) * HD + s * 32 + hi * 8);
            float4 v0 = src[0], v1 = src[1];
            short8 t;
            t[0] = (short)f2b(v0.x); t[1] = (short)f2b(v0.y);
            t[2] = (short)f2b(v0.z); t[3] = (short)f2b(v0.w);
            t[4] = (short)f2b(v1.x); t[5] = (short)f2b(v1.y);
            t[6] = (short)f2b(v1.z); t[7] = (short)f2b(v1.w);
            b[u][s] = t;
        }

    const int n  = rb0 >> 11;
    const int l0 = rb0 & (SEQ - 1);
    const size_t nh = (size_t)(n * HEADS + h);
    unsigned short* ob = out + nh * (SEQ * HD);

#pragma unroll
    for (int rt = 0; rt < 4; ++rt) {
        const int r0 = rb0 + rt * 16;
        short8 a[2];
#pragma unroll
        for (int s = 0; s < 2; ++s) {
            const float4* src = reinterpret_cast<const float4*>(
                X + (size_t)(r0 + lo) * EMBED + h * HD + s * 32 + hi * 8);
            float4 v0 = src[0], v1 = src[1];
            short8 t;
            t[0] = (short)f2b(v0.x); t[1] = (short)f2b(v0.y);
            t[2] = (short)f2b(v0.z); t[3] = (short)f2b(v0.w);
            t[4] = (short)f2b(v1.x); t[5] = (short)f2b(v1.y);
            t[6] = (short)f2b(v1.z); t[7] = (short)f2b(v1.w);
            a[s] = t;
        }

        f32x4 acc[4] = {};
#pragma unroll
        for (int u = 0; u < 4; ++u)
#pragma unroll
            for (int s = 0; s < 2; ++s)
                acc[u] = MFMA16(a[s], b[u][s], acc[u]);

#pragma unroll
        for (int u = 0; u < 4; ++u)
#pragma unroll
            for (int r = 0; r < 4; ++r)
                ob[(size_t)(l0 + rt * 16 + hi * 4 + r) * HD + 16 * u + lo] =
                    f2b(acc[u][r]);
    }
}

// ---------------------------------------------------------------------------
// Kernel 1b: V projection with transposed output [n*16+h][d][l].
// ---------------------------------------------------------------------------
__global__ __launch_bounds__(256) void projv_kernel(const float* __restrict__ X,
                                                    const float* __restrict__ W,
                                                    unsigned short* __restrict__ out) {
    const int tid = threadIdx.x;
    const int w = tid >> 6, lane = tid & 63;
    const int lo = lane & 15, hi = lane >> 4;
    const int r0 = blockIdx.x * 64;
    const int rw = r0 + w * 16;
    const int h  = blockIdx.y;

    __shared__ unsigned short T[64 * 73];

    short8 a[2];
#pragma unroll
    for (int s = 0; s < 2; ++s) {
        const float4* src = reinterpret_cast<const float4*>(
            X + (size_t)(rw + lo) * EMBED + h * HD + s * 32 + hi * 8);
        float4 v0 = src[0], v1 = src[1];
        short8 t;
        t[0] = (short)f2b(v0.x); t[1] = (short)f2b(v0.y);
        t[2] = (short)f2b(v0.z); t[3] = (short)f2b(v0.w);
        t[4] = (short)f2b(v1.x); t[5] = (short)f2b(v1.y);
        t[6] = (short)f2b(v1.z); t[7] = (short)f2b(v1.w);
        a[s] = t;
    }
    short8 b[4][2];
#pragma unroll
    for (int u = 0; u < 4; ++u)
#pragma unroll
        for (int s = 0; s < 2; ++s) {
            const float4* src = reinterpret_cast<const float4*>(
                W + (size_t)(16 * u + lo) * HD + s * 32 + hi * 8);
            float4 v0 = src[0], v1 = src[1];
            short8 t;
            t[0] = (short)f2b(v0.x); t[1] = (short)f2b(v0.y);
            t[2] = (short)f2b(v0.z); t[3] = (short)f2b(v0.w);
            t[4] = (short)f2b(v1.x); t[5] = (short)f2b(v1.y);
            t[6] = (short)f2b(v1.z); t[7] = (short)f2b(v1.w);
            b[u][s] = t;
        }

    f32x4 acc[4] = {};
#pragma unroll
    for (int u = 0; u < 4; ++u)
#pragma unroll
        for (int s = 0; s < 2; ++s)
            acc[u] = MFMA16(a[s], b[u][s], acc[u]);

#pragma unroll
    for (int u = 0; u < 4; ++u)
#pragma unroll
        for (int r = 0; r < 4; ++r)
            T[(w * 16 + hi * 4 + r) * 73 + 16 * u + lo] = f2b(acc[u][r]);
    __syncthreads();

    const int d = tid >> 2, lc = (tid & 3) * 16;
    const int n = r0 >> 11, l0 = r0 & (SEQ - 1);
    union { unsigned short s[16]; uint4 v[2]; } pk;
#pragma unroll
    for (int j = 0; j < 16; ++j) pk.s[j] = T[(lc + j) * 73 + d];
    unsigned short* dst = out + (size_t)(n * HEADS + h) * (HD * SEQ)
                              + (size_t)d * SEQ + l0 + lc;
    *reinterpret_cast<uint4*>(dst)     = pk.v[0];
    *reinterpret_cast<uint4*>(dst + 8) = pk.v[1];
}

// ---------------------------------------------------------------------------
// Kernel 2: flash attention — best/proven version (R20): padded linear LDS,
// KVB=32, dual-buffered single-barrier, pre-permuted V staging, static
// softmax shift, pk2 pack, QBLK=64 x 2 waves, grid (16, NH).
// ---------------------------------------------------------------------------
#define KST 72   // K LDS row stride (elems)
#define VST 40   // V LDS row stride (elems)

__global__ __launch_bounds__(128, 2) void attn_kernel(const unsigned short* __restrict__ Qb,
                                                      const unsigned short* __restrict__ Kb,
                                                      const unsigned short* __restrict__ Vt,
                                                      const unsigned* __restrict__ mbits,
                                                      unsigned short* __restrict__ Aout) {
    const int tid  = threadIdx.x;
    const int w    = tid >> 6;           // 0..1
    const int lane = tid & 63;
    const int lo = lane & 31, hi = lane >> 5;
    const int nhidx = blockIdx.y;
    const int n = nhidx >> 4, h = nhidx & 15;
    const int q0 = blockIdx.x * 128 + w * 64;

    const unsigned short* Qp = Qb + (size_t)nhidx * SEQ * HD;
    const unsigned short* Kp = Kb + (size_t)nhidx * SEQ * HD;
    const unsigned short* Vp = Vt + (size_t)nhidx * HD * SEQ;
    const unsigned* mb = mbits + n * (SEQ / 32);

    __shared__ __align__(16) unsigned short Klds[2][32 * KST];
    __shared__ __align__(16) unsigned short Vlds[2][64 * VST];

    // staging chunks: thread t owns chunks 2t, 2t+1 (same row, adjacent 16B)
    const int kr = (tid * 2) >> 3, kb0 = ((tid * 2) & 7) * 8;
    const int vr = (tid * 2) >> 2, vb0 = ((tid * 2) & 3) * 8;  // vb0 in {0,16}

    uint4 stK0, stK1, stV0, stV1;
#define LOADSTAGE(KB_)                                                        \
    {                                                                         \
        const unsigned short* kp_ = Kp + (size_t)((KB_) + kr) * HD + kb0;     \
        const unsigned short* vp_ = Vp + (size_t)vr * SEQ + (KB_) + vb0;      \
        stK0 = *reinterpret_cast<const uint4*>(kp_);                          \
        stK1 = *reinterpret_cast<const uint4*>(kp_ + 8);                      \
        stV0 = *reinterpret_cast<const uint4*>(vp_);                          \
        stV1 = *reinterpret_cast<const uint4*>(vp_ + 8);                      \
    }
    // V written pre-permuted within its 16-col group:
    //   lo-half = {V0.x,V0.y,V1.z,V1.w} ; hi-half = {V0.z,V0.w,V1.x,V1.y}
#define WRITESTAGE(BUF)                                                       \
    {                                                                         \
        *reinterpret_cast<uint4*>(&Klds[BUF][kr * KST + kb0])     = stK0;     \
        *reinterpret_cast<uint4*>(&Klds[BUF][kr * KST + kb0 + 8]) = stK1;     \
        uint4 pv0, pv1;                                                       \
        pv0.x = stV0.x; pv0.y = stV0.y; pv0.z = stV1.z; pv0.w = stV1.w;       \
        pv1.x = stV0.z; pv1.y = stV0.w; pv1.z = stV1.x; pv1.w = stV1.y;       \
        *reinterpret_cast<uint4*>(&Vlds[BUF][vr * VST + vb0])     = pv0;      \
        *reinterpret_cast<uint4*>(&Vlds[BUF][vr * VST + vb0 + 8]) = pv1;      \
    }

    // Q fragments (B-operand of swapped QK^T), two q-groups:
    //   A: col = q0+lo, B: col = q0+32+lo ; k=d = s*16 + hi*8 + j
    short8 qfA[4], qfB[4];
#pragma unroll
    for (int s = 0; s < 4; ++s) {
        qfA[s] = ld8(Qp + (size_t)(q0 + lo) * HD + s * 16 + hi * 8);
        qfB[s] = ld8(Qp + (size_t)(q0 + 32 + lo) * HD + s * 16 + hi * 8);
    }

    f32x16 o0A = {}, o1A = {}, o0B = {}, o1B = {};
    float lsumA = 0.0f, lsumB = 0.0f;

    const float KS    = 0.045084220027780106f;  // log2(e)/32
    const float M0    = 8.0f;                   // static softmax shift (exact)
    const float TMASK = -4.5e18f;               // exp2 -> 0

    LOADSTAGE(0)

    int cur = 0;
    for (int kt = 0; kt < SEQ / 32; ++kt) {
        WRITESTAGE(cur)
        if (kt + 1 < SEQ / 32) LOADSTAGE((kt + 1) * 32)
        __syncthreads();   // the ONLY barrier per tile

        const unsigned short* Kl = Klds[cur];
        const unsigned short* Vl = Vlds[cur];

        // S^T = K . Q^T : A-operand = K rows (row = k_local = lo), shared
        f32x16 saA = {}, saB = {};
#pragma unroll
        for (int s = 0; s < 4; ++s) {
            short8 kf = *reinterpret_cast<const short8*>(Kl + lo * KST + s * 16 + hi * 8);
            saA = MFMA32(kf, qfA[s], saA);
            saB = MFMA32(kf, qfB[s], saB);
        }

        // V^T fragments: ONE b128 each from the pre-permuted LDS layout
        short8 vf[2][2];
#pragma unroll
        for (int dt = 0; dt < 2; ++dt)
#pragma unroll
            for (int s = 0; s < 2; ++s)
                vf[dt][s] = *reinterpret_cast<const short8*>(
                    Vl + (32 * dt + lo) * VST + s * 16 + hi * 8);

        // masked, scaled, statically-shifted logits -> exp2 (both q-groups)
        unsigned mw = mb[kt] >> (4 * hi);
        float pA[16], pB[16];
#pragma unroll
        for (int r = 0; r < 16; ++r) {
            const int bp = (r & 3) + 8 * (r >> 2);
            const bool keep = (mw >> bp) & 1u;
            float ta = fmaf(saA[r], KS, -M0);
            float tb = fmaf(saB[r], KS, -M0);
            float ea = EXP2(keep ? ta : TMASK);
            float eb = EXP2(keep ? tb : TMASK);
            pA[r] = ea; lsumA += ea;
            pB[r] = eb; lsumB += eb;
        }

        // pack P and build P^T B-fragments (same pi permutation), per group
#define PACK_PB(P, PB_)                                                       \
        {                                                                     \
            unsigned W0[4], W1[4];                                            \
            _Pragma("unroll") for (int g = 0; g < 4; ++g) {                   \
                W0[g] = pk2(P[4 * g],     P[4 * g + 1]);                      \
                W1[g] = pk2(P[4 * g + 2], P[4 * g + 3]);                      \
            }                                                                 \
            _Pragma("unroll") for (int s2 = 0; s2 < 2; ++s2) {                \
                unsigned sw0 = (unsigned)__shfl_xor((int)W0[2 * s2 + 1], 32); \
                unsigned sw1 = (unsigned)__shfl_xor((int)W1[2 * s2 + 1], 32); \
                union { short8 s8; unsigned u[4]; } uu;                       \
                uu.u[0] = W0[2 * s2]; uu.u[1] = W1[2 * s2];                   \
                uu.u[2] = sw0;        uu.u[3] = sw1;                          \
                (PB_)[s2] = uu.s8;                                            \
            }                                                                 \
        }
        short8 pbA[2], pbB[2];
        PACK_PB(pA, pbA)
        PACK_PB(pB, pbB)
#undef PACK_PB

        // O^T += V^T . P^T  (V fragments shared across q-groups)
#pragma unroll
        for (int s = 0; s < 2; ++s) {
            o0A = MFMA32(vf[0][s], pbA[s], o0A);
            o1A = MFMA32(vf[1][s], pbA[s], o1A);
            o0B = MFMA32(vf[0][s], pbB[s], o0B);
            o1B = MFMA32(vf[1][s], pbB[s], o1B);
        }

        cur ^= 1;   // no end-of-loop barrier needed (disjoint buffers)
    }

    // final cross-half reduce of the denominators
    float lA = lsumA + __shfl_xor(lsumA, 32);
    float lB = lsumB + __shfl_xor(lsumB, 32);

    // epilogue: group A owns q = q0+lo, group B owns q = q0+32+lo
    float invA = 1.0f / lA;
    float invB = 1.0f / lB;
    const size_t rbA = (size_t)(n * SEQ + q0 + lo) * EMBED + h * HD;
    const size_t rbB = (size_t)(n * SEQ + q0 + 32 + lo) * EMBED + h * HD;
#pragma unroll
    for (int r = 0; r < 16; ++r) {
        int dl = (r & 3) + 8 * (r >> 2) + 4 * hi;
        Aout[rbA + dl]      = f2b(o0A[r] * invA);
        Aout[rbA + 32 + dl] = f2b(o1A[r] * invA);
        Aout[rbB + dl]      = f2b(o0B[r] * invB);
        Aout[rbB + 32 + dl] = f2b(o1B[r] * invB);
    }
#undef LOADSTAGE
#undef WRITESTAGE
}

// ---------------------------------------------------------------------------
// Kernel 3: Y = A(8192x1024) @ Wo.T + bo  (fp32 out), LDS-staged GEMM.
// Flat grid + XCD swizzle, tile 128x128, BK=32.
// ---------------------------------------------------------------------------
#define OST 40
__global__ __launch_bounds__(256, 2) void outproj_kernel(const unsigned short* __restrict__ A,
                                                         const unsigned short* __restrict__ Wob,
                                                         const float* __restrict__ bo,
                                                         float* __restrict__ Y) {
    const int tid  = threadIdx.x;
    const int w    = tid >> 6;
    const int lane = tid & 63;
    const int lo = lane & 15, hi = lane >> 4;

    const int bid = blockIdx.x;                    // 0..511
    const int swz = (bid & 7) * 64 + (bid >> 3);   // bijective bit-rotation
    const int r0 = (swz >> 3) * 128;
    const int c0 = (swz & 7) * 128;

    __shared__ __align__(16) unsigned short Al[128 * OST];
    __shared__ __align__(16) unsigned short Bl[128 * OST];

    const int srow = tid >> 2, scb = (tid & 3) * 8;
    uint4 sA0, sA1, sB0, sB1;
#define OLOAD(K_)                                                             \
    {                                                                         \
        sA0 = *reinterpret_cast<const uint4*>(A + (size_t)(r0 + srow) * EMBED + (K_) + scb);        \
        sA1 = *reinterpret_cast<const uint4*>(A + (size_t)(r0 + 64 + srow) * EMBED + (K_) + scb);   \
        sB0 = *reinterpret_cast<const uint4*>(Wob + (size_t)(c0 + srow) * EMBED + (K_) + scb);      \
        sB1 = *reinterpret_cast<const uint4*>(Wob + (size_t)(c0 + 64 + srow) * EMBED + (K_) + scb); \
    }
#define OWRITE()                                                              \
    {                                                                         \
        *reinterpret_cast<uint4*>(&Al[srow * OST + scb])        = sA0;        \
        *reinterpret_cast<uint4*>(&Al[(64 + srow) * OST + scb]) = sA1;        \
        *reinterpret_cast<uint4*>(&Bl[srow * OST + scb])        = sB0;        \
        *reinterpret_cast<uint4*>(&Bl[(64 + srow) * OST + scb]) = sB1;        \
    }

    f32x4 acc[2][8] = {};
    OLOAD(0)
    for (int kt = 0; kt < EMBED / 32; ++kt) {
        OWRITE()
        if (kt + 1 < EMBED / 32) OLOAD((kt + 1) * 32)
        __syncthreads();

        short8 a0 = ld8(&Al[(w * 32 + lo) * OST + hi * 8]);
        short8 a1 = ld8(&Al[(w * 32 + 16 + lo) * OST + hi * 8]);
#pragma unroll
        for (int u = 0; u < 8; ++u) {
            short8 b = ld8(&Bl[(u * 16 + lo) * OST + hi * 8]);
            acc[0][u] = MFMA16(a0, b, acc[0][u]);
            acc[1][u] = MFMA16(a1, b, acc[1][u]);
        }
        __syncthreads();
    }

#pragma unroll
    for (int mi = 0; mi < 2; ++mi)
#pragma unroll
        for (int u = 0; u < 8; ++u) {
            int e = c0 + u * 16 + lo;
            float bv = bo[e];
#pragma unroll
            for (int r = 0; r < 4; ++r)
                Y[(size_t)(r0 + w * 32 + mi * 16 + hi * 4 + r) * EMBED + e] =
                    acc[mi][u][r] + bv;
        }
#undef OLOAD
#undef OWRITE
}

// ---------------------------------------------------------------------------
extern "C" void kernel_launch(void* const* d_in, const int* in_sizes, int n_in,
                              void* d_out, int out_size, void* d_ws, size_t ws_size,
                              hipStream_t stream) {
    const float* values  = (const float*)d_in[0];
    const float* keys    = (const float*)d_in[1];
    const float* queries = (const float*)d_in[2];
    const int*   mask    = (const int*)d_in[3];
    const float* Wv = (const float*)d_in[4];
    const float* Wk = (const float*)d_in[5];
    const float* Wq = (const float*)d_in[6];
    const float* Wo = (const float*)d_in[7];
    const float* bo = (const float*)d_in[8];
    float* Y = (float*)d_out;

    const size_t QKV     = (size_t)NH * SEQ * HD * sizeof(unsigned short); // 16 MiB
    const size_t ABYTES  = (size_t)ROWS * EMBED * sizeof(unsigned short);  // 16 MiB
    const size_t WOBYTES = (size_t)EMBED * EMBED * sizeof(unsigned short); //  2 MiB
    const size_t MBYTES  = (size_t)NB * (SEQ / 32) * sizeof(unsigned);
    if (ws_size < 3 * QKV + ABYTES + WOBYTES + MBYTES) return;

    char* ws = (char*)d_ws;
    unsigned short* Qb  = (unsigned short*)(ws);
    unsigned short* Kb  = (unsigned short*)(ws + QKV);
    unsigned short* Vt  = (unsigned short*)(ws + 2 * QKV);
    unsigned short* Ab  = (unsigned short*)(ws + 3 * QKV);
    unsigned short* Wob = (unsigned short*)(ws + 3 * QKV + ABYTES);
    unsigned*       Mb  = (unsigned*)(ws + 3 * QKV + ABYTES + WOBYTES);

    cvtmask_kernel<<<dim3(1025), 256, 0, stream>>>(Wo, Wob, mask, Mb);
    projqk_kernel<<<dim3(ROWS / 64, HEADS, 2), 64, 0, stream>>>(queries, Wq, Qb,
                                                                keys, Wk, Kb);
    projv_kernel<<<dim3(ROWS / 64, HEADS), 256, 0, stream>>>(values, Wv, Vt);
    attn_kernel<<<dim3(SEQ / 128, NH), 128, 0, stream>>>(Qb, Kb, Vt, Mb, Ab);
    outproj_kernel<<<dim3(512), 256, 0, stream>>>(Ab, Wob, bo, Y);
}

// Round 24
// 179.495 us; speedup vs baseline: 1.1656x; 1.0043x over previous
//
#include <hip/hip_runtime.h>
#include <hip/hip_bf16.h>
#include <stdint.h>
#include <string.h>

#define EMBED 1024
#define HEADS 16
#define HD    64
#define SEQ   2048
#define NB    4
#define ROWS  (SEQ * NB)   // 8192
#define NH    (NB * HEADS) // 64

typedef __attribute__((ext_vector_type(8)))  short short8;   // 8 x bf16
typedef __attribute__((ext_vector_type(4)))  float f32x4;
typedef __attribute__((ext_vector_type(16))) float f32x16;
typedef __attribute__((ext_vector_type(4)))  unsigned short u16x4;

#define MFMA16(a, b, c) __builtin_amdgcn_mfma_f32_16x16x32_bf16((a), (b), (c), 0, 0, 0)
#define MFMA32(a, b, c) __builtin_amdgcn_mfma_f32_32x32x16_bf16((a), (b), (c), 0, 0, 0)

// fp32 -> bf16 bits, round-to-nearest-even
__device__ inline unsigned short f2b(float f) {
    unsigned u = __builtin_bit_cast(unsigned, f);
    u += 0x7fffu + ((u >> 16) & 1u);
    return (unsigned short)(u >> 16);
}

// packed pair fp32 -> bf16x2 via the COMPILER's conversion (RNE, lo = a).
__device__ inline unsigned pk2(float a, float b) {
    __hip_bfloat162 h = __float22bfloat162_rn(make_float2(a, b));
    unsigned r;
    __builtin_memcpy(&r, &h, 4);
    return r;
}

// raw v_exp_f32: D = 2^S0 (large-negative -> 0)
#define EXP2(x) __builtin_amdgcn_exp2f(x)

__device__ inline short8 ld8(const unsigned short* p) {
    return *reinterpret_cast<const short8*>(p);
}

// ---------------------------------------------------------------------------
// Kernel 0: merged fp32->bf16 cast (Wo, blocks 0..1023) + mask bit-pack
// (block 1024: 256 threads, one 32-k mask word each).
// ---------------------------------------------------------------------------
__global__ __launch_bounds__(256) void cvtmask_kernel(const float* __restrict__ in,
                                                      unsigned short* __restrict__ out,
                                                      const int* __restrict__ mask,
                                                      unsigned* __restrict__ mb) {
    const int bid = blockIdx.x;
    if (bid < 1024) {
        int i = (bid * 256 + threadIdx.x) * 4;
        float4 v = *reinterpret_cast<const float4*>(in + i);
        u16x4 o;
        o[0] = f2b(v.x); o[1] = f2b(v.y); o[2] = f2b(v.z); o[3] = f2b(v.w);
        *reinterpret_cast<u16x4*>(out + i) = o;
    } else {
        int w = threadIdx.x;   // 256 words total
        unsigned v = 0;
#pragma unroll
        for (int j = 0; j < 32; ++j)
            v |= (mask[w * 32 + j] != 0 ? 1u : 0u) << j;
        mb[w] = v;
    }
}

// ---------------------------------------------------------------------------
// Kernel 1: merged Q/K per-head projection  out = X_head @ W.T (MFMA 16x16x32)
// blockIdx.z selects (X, W, out). 64 rows per block (4 x 16-row sub-tiles;
// W converted ONCE). out layout [n*16+h][l][d]. grid (ROWS/64, HEADS, 2).
// ---------------------------------------------------------------------------
__global__ __launch_bounds__(64) void projqk_kernel(const float* __restrict__ Xq,
                                                    const float* __restrict__ Wq,
                                                    unsigned short* __restrict__ outq,
                                                    const float* __restrict__ Xk,
                                                    const float* __restrict__ Wk,
                                                    unsigned short* __restrict__ outk) {
    const float* X = blockIdx.z ? Xk : Xq;
    const float* W = blockIdx.z ? Wk : Wq;
    unsigned short* out = blockIdx.z ? outk : outq;

    const int lane = threadIdx.x;
    const int lo = lane & 15, hi = lane >> 4;
    const int rb0 = blockIdx.x * 64;
    const int h   = blockIdx.y;

    // B fragments: W converted once per block
    short8 b[4][2];
#pragma unroll
    for (int u = 0; u < 4; ++u)
#pragma unroll
        for (int s = 0; s < 2; ++s) {
            const float4* src = reinterpret_cast<const float4*>(
                W + (size_t)(16 * u + lo) * HD + s * 32 + hi * 8);
            float4 v0 = src[0], v1 = src[1];
            short8 t;
            t[0] = (short)f2b(v0.x); t[1] = (short)f2b(v0.y);
            t[2] = (short)f2b(v0.z); t[3] = (short)f2b(v0.w);
            t[4] = (short)f2b(v1.x); t[5] = (short)f2b(v1.y);
            t[6] = (short)f2b(v1.z); t[7] = (short)f2b(v1.w);
            b[u][s] = t;
        }

    const int n  = rb0 >> 11;
    const int l0 = rb0 & (SEQ - 1);
    const size_t nh = (size_t)(n * HEADS + h);
    unsigned short* ob = out + nh * (SEQ * HD);

#pragma unroll
    for (int rt = 0; rt < 4; ++rt) {
        const int r0 = rb0 + rt * 16;
        short8 a[2];
#pragma unroll
        for (int s = 0; s < 2; ++s) {
            const float4* src = reinterpret_cast<const float4*>(
                X + (size_t)(r0 + lo) * EMBED + h * HD + s * 32 + hi * 8);
            float4 v0 = src[0], v1 = src[1];
            short8 t;
            t[0] = (short)f2b(v0.x); t[1] = (short)f2b(v0.y);
            t[2] = (short)f2b(v0.z); t[3] = (short)f2b(v0.w);
            t[4] = (short)f2b(v1.x); t[5] = (short)f2b(v1.y);
            t[6] = (short)f2b(v1.z); t[7] = (short)f2b(v1.w);
            a[s] = t;
        }

        f32x4 acc[4] = {};
#pragma unroll
        for (int u = 0; u < 4; ++u)
#pragma unroll
            for (int s = 0; s < 2; ++s)
                acc[u] = MFMA16(a[s], b[u][s], acc[u]);

#pragma unroll
        for (int u = 0; u < 4; ++u)
#pragma unroll
            for (int r = 0; r < 4; ++r)
                ob[(size_t)(l0 + rt * 16 + hi * 4 + r) * HD + 16 * u + lo] =
                    f2b(acc[u][r]);
    }
}

// ---------------------------------------------------------------------------
// Kernel 1b: V projection with transposed output [n*16+h][d][l].
// ---------------------------------------------------------------------------
__global__ __launch_bounds__(256) void projv_kernel(const float* __restrict__ X,
                                                    const float* __restrict__ W,
                                                    unsigned short* __restrict__ out) {
    const int tid = threadIdx.x;
    const int w = tid >> 6, lane = tid & 63;
    const int lo = lane & 15, hi = lane >> 4;
    const int r0 = blockIdx.x * 64;
    const int rw = r0 + w * 16;
    const int h  = blockIdx.y;

    __shared__ unsigned short T[64 * 73];

    short8 a[2];
#pragma unroll
    for (int s = 0; s < 2; ++s) {
        const float4* src = reinterpret_cast<const float4*>(
            X + (size_t)(rw + lo) * EMBED + h * HD + s * 32 + hi * 8);
        float4 v0 = src[0], v1 = src[1];
        short8 t;
        t[0] = (short)f2b(v0.x); t[1] = (short)f2b(v0.y);
        t[2] = (short)f2b(v0.z); t[3] = (short)f2b(v0.w);
        t[4] = (short)f2b(v1.x); t[5] = (short)f2b(v1.y);
        t[6] = (short)f2b(v1.z); t[7] = (short)f2b(v1.w);
        a[s] = t;
    }
    short8 b[4][2];
#pragma unroll
    for (int u = 0; u < 4; ++u)
#pragma unroll
        for (int s = 0; s < 2; ++s) {
            const float4* src = reinterpret_cast<const float4*>(
                W + (size_t)(16 * u + lo) * HD + s * 32 + hi * 8);
            float4 v0 = src[0], v1 = src[1];
            short8 t;
            t[0] = (short)f2b(v0.x); t[1] = (short)f2b(v0.y);
            t[2] = (short)f2b(v0.z); t[3] = (short)f2b(v0.w);
            t[4] = (short)f2b(v1.x); t[5] = (short)f2b(v1.y);
            t[6] = (short)f2b(v1.z); t[7] = (short)f2b(v1.w);
            b[u][s] = t;
        }

    f32x4 acc[4] = {};
#pragma unroll
    for (int u = 0; u < 4; ++u)
#pragma unroll
        for (int s = 0; s < 2; ++s)
            acc[u] = MFMA16(a[s], b[u][s], acc[u]);

#pragma unroll
    for (int u = 0; u < 4; ++u)
#pragma unroll
        for (int r = 0; r < 4; ++r)
            T[(w * 16 + hi * 4 + r) * 73 + 16 * u + lo] = f2b(acc[u][r]);
    __syncthreads();

    const int d = tid >> 2, lc = (tid & 3) * 16;
    const int n = r0 >> 11, l0 = r0 & (SEQ - 1);
    union { unsigned short s[16]; uint4 v[2]; } pk;
#pragma unroll
    for (int j = 0; j < 16; ++j) pk.s[j] = T[(lc + j) * 73 + d];
    unsigned short* dst = out + (size_t)(n * HEADS + h) * (HD * SEQ)
                              + (size_t)d * SEQ + l0 + lc;
    *reinterpret_cast<uint4*>(dst)     = pk.v[0];
    *reinterpret_cast<uint4*>(dst + 8) = pk.v[1];
}

// ---------------------------------------------------------------------------
// Kernel 2: flash attention — R20/best structure; ONLY delta this round:
// vectorized epilogue (pk2 pairs -> 16 x uint2 stores instead of 64 scalar).
// ---------------------------------------------------------------------------
#define KST 72   // K LDS row stride (elems)
#define VST 40   // V LDS row stride (elems)

__global__ __launch_bounds__(128, 2) void attn_kernel(const unsigned short* __restrict__ Qb,
                                                      const unsigned short* __restrict__ Kb,
                                                      const unsigned short* __restrict__ Vt,
                                                      const unsigned* __restrict__ mbits,
                                                      unsigned short* __restrict__ Aout) {
    const int tid  = threadIdx.x;
    const int w    = tid >> 6;           // 0..1
    const int lane = tid & 63;
    const int lo = lane & 31, hi = lane >> 5;
    const int nhidx = blockIdx.y;
    const int n = nhidx >> 4, h = nhidx & 15;
    const int q0 = blockIdx.x * 128 + w * 64;

    const unsigned short* Qp = Qb + (size_t)nhidx * SEQ * HD;
    const unsigned short* Kp = Kb + (size_t)nhidx * SEQ * HD;
    const unsigned short* Vp = Vt + (size_t)nhidx * HD * SEQ;
    const unsigned* mb = mbits + n * (SEQ / 32);

    __shared__ __align__(16) unsigned short Klds[2][32 * KST];
    __shared__ __align__(16) unsigned short Vlds[2][64 * VST];

    // staging chunks: thread t owns chunks 2t, 2t+1 (same row, adjacent 16B)
    const int kr = (tid * 2) >> 3, kb0 = ((tid * 2) & 7) * 8;
    const int vr = (tid * 2) >> 2, vb0 = ((tid * 2) & 3) * 8;  // vb0 in {0,16}

    uint4 stK0, stK1, stV0, stV1;
#define LOADSTAGE(KB_)                                                        \
    {                                                                         \
        const unsigned short* kp_ = Kp + (size_t)((KB_) + kr) * HD + kb0;     \
        const unsigned short* vp_ = Vp + (size_t)vr * SEQ + (KB_) + vb0;      \
        stK0 = *reinterpret_cast<const uint4*>(kp_);                          \
        stK1 = *reinterpret_cast<const uint4*>(kp_ + 8);                      \
        stV0 = *reinterpret_cast<const uint4*>(vp_);                          \
        stV1 = *reinterpret_cast<const uint4*>(vp_ + 8);                      \
    }
    // V written pre-permuted within its 16-col group:
    //   lo-half = {V0.x,V0.y,V1.z,V1.w} ; hi-half = {V0.z,V0.w,V1.x,V1.y}
#define WRITESTAGE(BUF)                                                       \
    {                                                                         \
        *reinterpret_cast<uint4*>(&Klds[BUF][kr * KST + kb0])     = stK0;     \
        *reinterpret_cast<uint4*>(&Klds[BUF][kr * KST + kb0 + 8]) = stK1;     \
        uint4 pv0, pv1;                                                       \
        pv0.x = stV0.x; pv0.y = stV0.y; pv0.z = stV1.z; pv0.w = stV1.w;       \
        pv1.x = stV0.z; pv1.y = stV0.w; pv1.z = stV1.x; pv1.w = stV1.y;       \
        *reinterpret_cast<uint4*>(&Vlds[BUF][vr * VST + vb0])     = pv0;      \
        *reinterpret_cast<uint4*>(&Vlds[BUF][vr * VST + vb0 + 8]) = pv1;      \
    }

    // Q fragments (B-operand of swapped QK^T), two q-groups:
    //   A: col = q0+lo, B: col = q0+32+lo ; k=d = s*16 + hi*8 + j
    short8 qfA[4], qfB[4];
#pragma unroll
    for (int s = 0; s < 4; ++s) {
        qfA[s] = ld8(Qp + (size_t)(q0 + lo) * HD + s * 16 + hi * 8);
        qfB[s] = ld8(Qp + (size_t)(q0 + 32 + lo) * HD + s * 16 + hi * 8);
    }

    f32x16 o0A = {}, o1A = {}, o0B = {}, o1B = {};
    float lsumA = 0.0f, lsumB = 0.0f;

    const float KS    = 0.045084220027780106f;  // log2(e)/32
    const float M0    = 8.0f;                   // static softmax shift (exact)
    const float TMASK = -4.5e18f;               // exp2 -> 0

    LOADSTAGE(0)

    int cur = 0;
    for (int kt = 0; kt < SEQ / 32; ++kt) {
        WRITESTAGE(cur)
        if (kt + 1 < SEQ / 32) LOADSTAGE((kt + 1) * 32)
        __syncthreads();   // the ONLY barrier per tile

        const unsigned short* Kl = Klds[cur];
        const unsigned short* Vl = Vlds[cur];

        // S^T = K . Q^T : A-operand = K rows (row = k_local = lo), shared
        f32x16 saA = {}, saB = {};
#pragma unroll
        for (int s = 0; s < 4; ++s) {
            short8 kf = *reinterpret_cast<const short8*>(Kl + lo * KST + s * 16 + hi * 8);
            saA = MFMA32(kf, qfA[s], saA);
            saB = MFMA32(kf, qfB[s], saB);
        }

        // V^T fragments: ONE b128 each from the pre-permuted LDS layout
        short8 vf[2][2];
#pragma unroll
        for (int dt = 0; dt < 2; ++dt)
#pragma unroll
            for (int s = 0; s < 2; ++s)
                vf[dt][s] = *reinterpret_cast<const short8*>(
                    Vl + (32 * dt + lo) * VST + s * 16 + hi * 8);

        // masked, scaled, statically-shifted logits -> exp2 (both q-groups)
        unsigned mw = mb[kt] >> (4 * hi);
        float pA[16], pB[16];
#pragma unroll
        for (int r = 0; r < 16; ++r) {
            const int bp = (r & 3) + 8 * (r >> 2);
            const bool keep = (mw >> bp) & 1u;
            float ta = fmaf(saA[r], KS, -M0);
            float tb = fmaf(saB[r], KS, -M0);
            float ea = EXP2(keep ? ta : TMASK);
            float eb = EXP2(keep ? tb : TMASK);
            pA[r] = ea; lsumA += ea;
            pB[r] = eb; lsumB += eb;
        }

        // pack P and build P^T B-fragments (same pi permutation), per group
#define PACK_PB(P, PB_)                                                       \
        {                                                                     \
            unsigned W0[4], W1[4];                                            \
            _Pragma("unroll") for (int g = 0; g < 4; ++g) {                   \
                W0[g] = pk2(P[4 * g],     P[4 * g + 1]);                      \
                W1[g] = pk2(P[4 * g + 2], P[4 * g + 3]);                      \
            }                                                                 \
            _Pragma("unroll") for (int s2 = 0; s2 < 2; ++s2) {                \
                unsigned sw0 = (unsigned)__shfl_xor((int)W0[2 * s2 + 1], 32); \
                unsigned sw1 = (unsigned)__shfl_xor((int)W1[2 * s2 + 1], 32); \
                union { short8 s8; unsigned u[4]; } uu;                       \
                uu.u[0] = W0[2 * s2]; uu.u[1] = W1[2 * s2];                   \
                uu.u[2] = sw0;        uu.u[3] = sw1;                          \
                (PB_)[s2] = uu.s8;                                            \
            }                                                                 \
        }
        short8 pbA[2], pbB[2];
        PACK_PB(pA, pbA)
        PACK_PB(pB, pbB)
#undef PACK_PB

        // O^T += V^T . P^T  (V fragments shared across q-groups)
#pragma unroll
        for (int s = 0; s < 2; ++s) {
            o0A = MFMA32(vf[0][s], pbA[s], o0A);
            o1A = MFMA32(vf[1][s], pbA[s], o1A);
            o0B = MFMA32(vf[0][s], pbB[s], o0B);
            o1B = MFMA32(vf[1][s], pbB[s], o1B);
        }

        cur ^= 1;   // no end-of-loop barrier needed (disjoint buffers)
    }

    // final cross-half reduce of the denominators
    float lA = lsumA + __shfl_xor(lsumA, 32);
    float lB = lsumB + __shfl_xor(lsumB, 32);

    // epilogue (vectorized): quartet g covers d = 8g + 4hi + {0..3};
    // pack with pk2 (proven lo=a) -> one 8B uint2 store per (group, dtile, g)
    float invA = 1.0f / lA;
    float invB = 1.0f / lB;
    const size_t rbA = (size_t)(n * SEQ + q0 + lo) * EMBED + h * HD;
    const size_t rbB = (size_t)(n * SEQ + q0 + 32 + lo) * EMBED + h * HD;
#pragma unroll
    for (int g = 0; g < 4; ++g) {
        const int off = 8 * g + 4 * hi;
        uint2 v;
        v.x = pk2(o0A[4 * g] * invA,     o0A[4 * g + 1] * invA);
        v.y = pk2(o0A[4 * g + 2] * invA, o0A[4 * g + 3] * invA);
        *reinterpret_cast<uint2*>(Aout + rbA + off) = v;
        v.x = pk2(o1A[4 * g] * invA,     o1A[4 * g + 1] * invA);
        v.y = pk2(o1A[4 * g + 2] * invA, o1A[4 * g + 3] * invA);
        *reinterpret_cast<uint2*>(Aout + rbA + 32 + off) = v;
        v.x = pk2(o0B[4 * g] * invB,     o0B[4 * g + 1] * invB);
        v.y = pk2(o0B[4 * g + 2] * invB, o0B[4 * g + 3] * invB);
        *reinterpret_cast<uint2*>(Aout + rbB + off) = v;
        v.x = pk2(o1B[4 * g] * invB,     o1B[4 * g + 1] * invB);
        v.y = pk2(o1B[4 * g + 2] * invB, o1B[4 * g + 3] * invB);
        *reinterpret_cast<uint2*>(Aout + rbB + 32 + off) = v;
    }
#undef LOADSTAGE
#undef WRITESTAGE
}

// ---------------------------------------------------------------------------
// Kernel 3: Y = A(8192x1024) @ Wo.T + bo  (fp32 out), LDS-staged GEMM.
// Flat grid + XCD swizzle, tile 128x128, BK=32.
// ---------------------------------------------------------------------------
#define OST 40
__global__ __launch_bounds__(256, 2) void outproj_kernel(const unsigned short* __restrict__ A,
                                                         const unsigned short* __restrict__ Wob,
                                                         const float* __restrict__ bo,
                                                         float* __restrict__ Y) {
    const int tid  = threadIdx.x;
    const int w    = tid >> 6;
    const int lane = tid & 63;
    const int lo = lane & 15, hi = lane >> 4;

    const int bid = blockIdx.x;                    // 0..511
    const int swz = (bid & 7) * 64 + (bid >> 3);   // bijective bit-rotation
    const int r0 = (swz >> 3) * 128;
    const int c0 = (swz & 7) * 128;

    __shared__ __align__(16) unsigned short Al[128 * OST];
    __shared__ __align__(16) unsigned short Bl[128 * OST];

    const int srow = tid >> 2, scb = (tid & 3) * 8;
    uint4 sA0, sA1, sB0, sB1;
#define OLOAD(K_)                                                             \
    {                                                                         \
        sA0 = *reinterpret_cast<const uint4*>(A + (size_t)(r0 + srow) * EMBED + (K_) + scb);        \
        sA1 = *reinterpret_cast<const uint4*>(A + (size_t)(r0 + 64 + srow) * EMBED + (K_) + scb);   \
        sB0 = *reinterpret_cast<const uint4*>(Wob + (size_t)(c0 + srow) * EMBED + (K_) + scb);      \
        sB1 = *reinterpret_cast<const uint4*>(Wob + (size_t)(c0 + 64 + srow) * EMBED + (K_) + scb); \
    }
#define OWRITE()                                                              \
    {                                                                         \
        *reinterpret_cast<uint4*>(&Al[srow * OST + scb])        = sA0;        \
        *reinterpret_cast<uint4*>(&Al[(64 + srow) * OST + scb]) = sA1;        \
        *reinterpret_cast<uint4*>(&Bl[srow * OST + scb])        = sB0;        \
        *reinterpret_cast<uint4*>(&Bl[(64 + srow) * OST + scb]) = sB1;        \
    }

    f32x4 acc[2][8] = {};
    OLOAD(0)
    for (int kt = 0; kt < EMBED / 32; ++kt) {
        OWRITE()
        if (kt + 1 < EMBED / 32) OLOAD((kt + 1) * 32)
        __syncthreads();

        short8 a0 = ld8(&Al[(w * 32 + lo) * OST + hi * 8]);
        short8 a1 = ld8(&Al[(w * 32 + 16 + lo) * OST + hi * 8]);
#pragma unroll
        for (int u = 0; u < 8; ++u) {
            short8 b = ld8(&Bl[(u * 16 + lo) * OST + hi * 8]);
            acc[0][u] = MFMA16(a0, b, acc[0][u]);
            acc[1][u] = MFMA16(a1, b, acc[1][u]);
        }
        __syncthreads();
    }

#pragma unroll
    for (int mi = 0; mi < 2; ++mi)
#pragma unroll
        for (int u = 0; u < 8; ++u) {
            int e = c0 + u * 16 + lo;
            float bv = bo[e];
#pragma unroll
            for (int r = 0; r < 4; ++r)
                Y[(size_t)(r0 + w * 32 + mi * 16 + hi * 4 + r) * EMBED + e] =
                    acc[mi][u][r] + bv;
        }
#undef OLOAD
#undef OWRITE
}

// ---------------------------------------------------------------------------
extern "C" void kernel_launch(void* const* d_in, const int* in_sizes, int n_in,
                              void* d_out, int out_size, void* d_ws, size_t ws_size,
                              hipStream_t stream) {
    const float* values  = (const float*)d_in[0];
    const float* keys    = (const float*)d_in[1];
    const float* queries = (const float*)d_in[2];
    const int*   mask    = (const int*)d_in[3];
    const float* Wv = (const float*)d_in[4];
    const float* Wk = (const float*)d_in[5];
    const float* Wq = (const float*)d_in[6];
    const float* Wo = (const float*)d_in[7];
    const float* bo = (const float*)d_in[8];
    float* Y = (float*)d_out;

    const size_t QKV     = (size_t)NH * SEQ * HD * sizeof(unsigned short); // 16 MiB
    const size_t ABYTES  = (size_t)ROWS * EMBED * sizeof(unsigned short);  // 16 MiB
    const size_t WOBYTES = (size_t)EMBED * EMBED * sizeof(unsigned short); //  2 MiB
    const size_t MBYTES  = (size_t)NB * (SEQ / 32) * sizeof(unsigned);
    if (ws_size < 3 * QKV + ABYTES + WOBYTES + MBYTES) return;

    char* ws = (char*)d_ws;
    unsigned short* Qb  = (unsigned short*)(ws);
    unsigned short* Kb  = (unsigned short*)(ws + QKV);
    unsigned short* Vt  = (unsigned short*)(ws + 2 * QKV);
    unsigned short* Ab  = (unsigned short*)(ws + 3 * QKV);
    unsigned short* Wob = (unsigned short*)(ws + 3 * QKV + ABYTES);
    unsigned*       Mb  = (unsigned*)(ws + 3 * QKV + ABYTES + WOBYTES);

    cvtmask_kernel<<<dim3(1025), 256, 0, stream>>>(Wo, Wob, mask, Mb);
    projqk_kernel<<<dim3(ROWS / 64, HEADS, 2), 64, 0, stream>>>(queries, Wq, Qb,
                                                                keys, Wk, Kb);
    projv_kernel<<<dim3(ROWS / 64, HEADS), 256, 0, stream>>>(values, Wv, Vt);
    attn_kernel<<<dim3(SEQ / 128, NH), 128, 0, stream>>>(Qb, Kb, Vt, Mb, Ab);
    outproj_kernel<<<dim3(512), 256, 0, stream>>>(Ab, Wob, bo, Y);
}